// Round 3
// baseline (106.070 us; speedup 1.0000x reference)
//
#include <hip/hip_runtime.h>
#include <math.h>

#define NT 2560
#define DF 32
#define NB 4
#define SELF_EPS 0.5f
#define MS 8                 // m-split across blocks (each writes its own partial)
#define MROWS (NT / MS)      // 320 m rows per block
#define MT 64                // m tile
#define MITERS (MROWS / MT)  // 5
#define TN 64                // n rows per block (4 waves x 16)

typedef __attribute__((ext_vector_type(8))) short bf16x8;
typedef __attribute__((ext_vector_type(4))) float f32x4;

__device__ __forceinline__ unsigned short f2bf(float f) {
    unsigned u = __builtin_bit_cast(unsigned, f);
    u += 0x7fffu + ((u >> 16) & 1u);   // RNE
    return (unsigned short)(u >> 16);
}

__device__ __forceinline__ float fast_rcp(float x) {
#if __has_builtin(__builtin_amdgcn_rcpf)
    return __builtin_amdgcn_rcpf(x);
#else
    return 1.0f / x;
#endif
}

__device__ __forceinline__ float fast_exp2(float x) {
#if __has_builtin(__builtin_amdgcn_exp2f)
    return __builtin_amdgcn_exp2f(x);
#else
    return exp2f(x);
#endif
}

// tanh(relu(x)) = 1 - 2/(exp2(2*log2e*x)+1) for x>=0  -> 6 VALU ops
__device__ __forceinline__ float tanh_relu(float x) {
    float m = fmaxf(x, 0.0f);
    float e = fast_exp2(m * 2.885390082f);   // 2*log2(e)
    return 1.0f - 2.0f * fast_rcp(e + 1.0f);
}

// ---------------------------------------------------------------------------
// prep: convert X fp32 -> Xb bf16 row-major [B][NT][32] and XT bf16 [B][32][NT]
// ---------------------------------------------------------------------------
__global__ __launch_bounds__(256, 4)
void prep(const float* __restrict__ X,
          unsigned short* __restrict__ Xb, unsigned short* __restrict__ XT)
{
    const int t = threadIdx.x;
    __shared__ float sT[32][33];
    const int tile = blockIdx.x;
    const int b = tile / 80, n0 = (tile % 80) * 32;
    const int row = t >> 3, c4 = (t & 7) * 4;
    const size_t rbase = ((size_t)(b * NT + n0 + row)) * DF + c4;
    const float4 v = *(const float4*)(X + rbase);
    unsigned p0 = (unsigned)f2bf(v.x) | ((unsigned)f2bf(v.y) << 16);
    unsigned p1 = (unsigned)f2bf(v.z) | ((unsigned)f2bf(v.w) << 16);
    *(uint2*)(Xb + rbase) = make_uint2(p0, p1);
    sT[row][c4 + 0] = v.x; sT[row][c4 + 1] = v.y;
    sT[row][c4 + 2] = v.z; sT[row][c4 + 3] = v.w;
    __syncthreads();
    const int d = t >> 3, nq = (t & 7) * 4;
    unsigned q0 = (unsigned)f2bf(sT[nq + 0][d]) | ((unsigned)f2bf(sT[nq + 1][d]) << 16);
    unsigned q1 = (unsigned)f2bf(sT[nq + 2][d]) | ((unsigned)f2bf(sT[nq + 3][d]) << 16);
    *(uint2*)(XT + ((size_t)(b * DF + d)) * NT + n0 + nq) = make_uint2(q0, q1);
}

// ---------------------------------------------------------------------------
// main: per block, n-tile of 64 rows x m-slice of 320 rows.
// scores via mfma(A=Xm,B=Xn) -> per-wave row-major S in LDS (b64 writes),
// agg via mfma(A=S,B=H^T) accumulated in regs, plain stores to partial buffer.
// ---------------------------------------------------------------------------
__global__ __launch_bounds__(256, 4)
void gsage_main(const unsigned short* __restrict__ Xb,  // [B][NT][32] bf16
                const unsigned short* __restrict__ HT,  // [B][32][NT] bf16
                float* __restrict__ part)               // [MS][B][NT][32] fp32
{
    __shared__ unsigned short XmL[64 * 40];       // pad 40 (80B rows)
    __shared__ unsigned short HtL[32 * 72];       // pad 72 (144B rows)
    __shared__ unsigned short Ss[4 * 16 * 72];    // per-wave 16n x 64m (pad 72)

    const int t = threadIdx.x;
    const int w = t >> 6, lane = t & 63;
    const int q = lane >> 4, c = lane & 15;
    const int n0 = blockIdx.x * TN;
    const int slice = blockIdx.y;
    const int mbase = slice * MROWS;
    const int b = blockIdx.z;

    const size_t xbase = (size_t)b * NT * DF;   // elem offsets (row-major)
    const size_t tbase = (size_t)b * DF * NT;   // elem offsets (transposed)

    // score B-frag: Xn[n = n0+w*16+c][k = q*8 .. q*8+7], constant over m-loop
    const bf16x8 bfn = *(const bf16x8*)(Xb + xbase + (size_t)(n0 + w * 16 + c) * DF + q * 8);

    f32x4 acc0 = {0.f, 0.f, 0.f, 0.f};
    f32x4 acc1 = {0.f, 0.f, 0.f, 0.f};

    const int xrow = t >> 2, xseg = t & 3;   // Xm stage: 64 rows, 4 x 16B
    const int hrow = t >> 3, hseg = t & 7;   // HT stage: 32 rows, 8 x 16B

    uint4 xv = *(const uint4*)(Xb + xbase + (size_t)(mbase + xrow) * DF + xseg * 8);
    uint4 hv = *(const uint4*)(HT + tbase + (size_t)hrow * NT + mbase + hseg * 8);

    const int n_g = n0 + w * 16 + c;
    unsigned short* SsW = Ss + w * (16 * 72);

    for (int it = 0; it < MITERS; ++it) {
        const int m0 = mbase + it * MT;
        __syncthreads();                       // prior iter done reading LDS
        *(uint4*)(XmL + xrow * 40 + xseg * 8) = xv;
        *(uint4*)(HtL + hrow * 72 + hseg * 8) = hv;
        if (it + 1 < MITERS) {
            const int m1 = m0 + MT;
            xv = *(const uint4*)(Xb + xbase + (size_t)(m1 + xrow) * DF + xseg * 8);
            hv = *(const uint4*)(HT + tbase + (size_t)hrow * NT + m1 + hseg * 8);
        }
        __syncthreads();                       // tiles staged

        // ---- scores: lane holds S[n=c][m = m0 + t4*16 + q*4 + r] ----
        #pragma unroll
        for (int t4 = 0; t4 < 4; ++t4) {
            const bf16x8 af = *(const bf16x8*)(XmL + (t4 * 16 + c) * 40 + q * 8);
            const f32x4 zero = {0.f, 0.f, 0.f, 0.f};
            f32x4 st = __builtin_amdgcn_mfma_f32_16x16x32_bf16(af, bfn, zero, 0, 0, 0);
            float v0 = tanh_relu(st[0]);
            float v1 = tanh_relu(st[1]);
            float v2 = tanh_relu(st[2]);
            float v3 = tanh_relu(st[3]);
            // self-loop: this (q,c) holds diag elems only if tile is on the
            // diagonal and q == c>>2; then reg r == c&3 is the diagonal one.
            if ((n0 + w * 16 == m0 + t4 * 16) && (q == (c >> 2))) {
                const int r = c & 3;
                v0 += (r == 0) ? SELF_EPS : 0.f;
                v1 += (r == 1) ? SELF_EPS : 0.f;
                v2 += (r == 2) ? SELF_EPS : 0.f;
                v3 += (r == 3) ? SELF_EPS : 0.f;
            }
            unsigned p0 = (unsigned)f2bf(v0) | ((unsigned)f2bf(v1) << 16);
            unsigned p1 = (unsigned)f2bf(v2) | ((unsigned)f2bf(v3) << 16);
            *(uint2*)(SsW + c * 72 + t4 * 16 + q * 4) = make_uint2(p0, p1);
        }
        // cross-lane S visibility within the wave: drain LDS writes
        asm volatile("s_waitcnt lgkmcnt(0)" ::: "memory");

        // ---- agg: acc[n][d] += S[n][m] * H[m][d], K=64 in 2 chunks ----
        #pragma unroll
        for (int kc = 0; kc < 2; ++kc) {
            const bf16x8 sf = *(const bf16x8*)(SsW + c * 72 + kc * 32 + q * 8);
            const bf16x8 h0 = *(const bf16x8*)(HtL + c * 72 + kc * 32 + q * 8);
            const bf16x8 h1 = *(const bf16x8*)(HtL + (16 + c) * 72 + kc * 32 + q * 8);
            acc0 = __builtin_amdgcn_mfma_f32_16x16x32_bf16(sf, h0, acc0, 0, 0, 0);
            acc1 = __builtin_amdgcn_mfma_f32_16x16x32_bf16(sf, h1, acc1, 0, 0, 0);
        }
    }

    // C-layout: row n = n0+w*16+q*4+r, col d = c / c+16. Plain stores into
    // this slice's private partial buffer (no atomics, no zero-init needed).
    float* pp = part + ((size_t)slice * NB) * NT * DF + xbase
                     + (size_t)(n0 + w * 16 + q * 4) * DF + c;
    #pragma unroll
    for (int r = 0; r < 4; ++r) {
        pp[(size_t)r * DF]      = acc0[r];
        pp[(size_t)r * DF + 16] = acc1[r];
    }
}

// ---------------------------------------------------------------------------
// epilogue: agg = sum of 8 partials; Hout = elu(Hin*Ws + agg*Wn + b);
// optionally emit Hout^T bf16 for the next layer's aggregation.
// ---------------------------------------------------------------------------
__global__ __launch_bounds__(256, 4)
void gsage_epi(const float* __restrict__ Hin, const float* __restrict__ part,
               const float* __restrict__ Wsl, const float* __restrict__ Wnl,
               const float* __restrict__ bl,
               float* __restrict__ Hout, unsigned short* __restrict__ HTout)
{
    __shared__ float sW[32][33], sN[32][33], sH[32][36], sA[32][36], sT[32][33];
    const int t = threadIdx.x;
    const int n0 = blockIdx.x * 32;
    const int b = blockIdx.y;
    const int row = t >> 3, c4 = (t & 7) * 4;
    const size_t rb = ((size_t)(b * NT + n0 + row)) * DF + c4;
    const float4 hv = *(const float4*)(Hin + rb);
    float4 av = make_float4(0.f, 0.f, 0.f, 0.f);
    #pragma unroll
    for (int s = 0; s < MS; ++s) {
        const float4 v = *(const float4*)(part + (size_t)s * NB * NT * DF + rb);
        av.x += v.x; av.y += v.y; av.z += v.z; av.w += v.w;
    }
    const float4 w0 = *(const float4*)(Wsl + row * DF + c4);
    const float4 w1 = *(const float4*)(Wnl + row * DF + c4);
    sH[row][c4+0]=hv.x; sH[row][c4+1]=hv.y; sH[row][c4+2]=hv.z; sH[row][c4+3]=hv.w;
    sA[row][c4+0]=av.x; sA[row][c4+1]=av.y; sA[row][c4+2]=av.z; sA[row][c4+3]=av.w;
    sW[row][c4+0]=w0.x; sW[row][c4+1]=w0.y; sW[row][c4+2]=w0.z; sW[row][c4+3]=w0.w;
    sN[row][c4+0]=w1.x; sN[row][c4+1]=w1.y; sN[row][c4+2]=w1.z; sN[row][c4+3]=w1.w;
    __syncthreads();

    float4 z = make_float4(bl[c4+0], bl[c4+1], bl[c4+2], bl[c4+3]);
    #pragma unroll
    for (int k = 0; k < DF; ++k) {
        const float hk = sH[row][k], ak = sA[row][k];
        z.x += hk * sW[k][c4+0] + ak * sN[k][c4+0];
        z.y += hk * sW[k][c4+1] + ak * sN[k][c4+1];
        z.z += hk * sW[k][c4+2] + ak * sN[k][c4+2];
        z.w += hk * sW[k][c4+3] + ak * sN[k][c4+3];
    }
    z.x = z.x > 0.f ? z.x : __expf(z.x) - 1.f;
    z.y = z.y > 0.f ? z.y : __expf(z.y) - 1.f;
    z.z = z.z > 0.f ? z.z : __expf(z.z) - 1.f;
    z.w = z.w > 0.f ? z.w : __expf(z.w) - 1.f;
    *(float4*)(Hout + rb) = z;

    if (HTout != nullptr) {
        sT[row][c4+0]=z.x; sT[row][c4+1]=z.y; sT[row][c4+2]=z.z; sT[row][c4+3]=z.w;
        __syncthreads();
        const int d = t >> 3, nq = (t & 7) * 4;
        unsigned q0 = (unsigned)f2bf(sT[nq+0][d]) | ((unsigned)f2bf(sT[nq+1][d]) << 16);
        unsigned q1 = (unsigned)f2bf(sT[nq+2][d]) | ((unsigned)f2bf(sT[nq+3][d]) << 16);
        *(uint2*)(HTout + ((size_t)(b * DF + d)) * NT + n0 + nq) = make_uint2(q0, q1);
    }
}

extern "C" void kernel_launch(void* const* d_in, const int* in_sizes, int n_in,
                              void* d_out, int out_size, void* d_ws, size_t ws_size,
                              hipStream_t stream) {
    const float* X  = (const float*)d_in[0];
    const float* Ws = (const float*)d_in[1];   // [2][32][32]
    const float* Wn = (const float*)d_in[2];   // [2][32][32]
    const float* bv = (const float*)d_in[3];   // [2][32]
    float* out = (float*)d_out;

    char* ws = (char*)d_ws;
    float* part = (float*)ws;                              // 8*1.31MB = 10,485,760 B
    float* h1   = part + (size_t)MS * NB * NT * DF;        // 1,310,720 B
    unsigned short* Xb  = (unsigned short*)(ws + 11796480); // 655,360 B
    unsigned short* XT  = Xb + (size_t)NB * NT * DF;        // 655,360 B
    unsigned short* H1T = XT + (size_t)NB * NT * DF;        // 655,360 B

    prep<<<320, 256, 0, stream>>>(X, Xb, XT);

    dim3 g(NT / TN, MS, NB);   // 40 x 8 x 4 = 1280 blocks
    gsage_main<<<g, 256, 0, stream>>>(Xb, XT, part);
    gsage_epi<<<dim3(NT / 32, NB), 256, 0, stream>>>(X, part, Ws, Wn, bv, h1, H1T);
    gsage_main<<<g, 256, 0, stream>>>(Xb, H1T, part);
    gsage_epi<<<dim3(NT / 32, NB), 256, 0, stream>>>(h1, part, Ws + DF * DF, Wn + DF * DF,
                                                     bv + DF, out, nullptr);
}